// Round 1
// baseline (1710.459 us; speedup 1.0000x reference)
//
#include <hip/hip_runtime.h>
#include <math.h>

// Problem constants (match reference)
#define BATCH 16
#define NPTS  8192
#define FEATC 384
#define NG    512
#define KM    32

// d_out layout (flat float32, concatenated in return order)
#define OUT0_OFF 0                              // neighborhood [16,512,32,3] = 786432
#define OUT1_OFF (BATCH * NG * KM * 3)          // center       [16,512,3]   = 24576
#define OUT2_OFF (OUT1_OFF + BATCH * NG * 3)    // feature_group[16,512,32,384]

// Disable FP contraction so mul/add rounding matches the numpy/XLA-CPU reference.
#pragma clang fp contract(off)

// ---------------------------------------------------------------------------
// Kernel A: farthest point sampling. One block per batch. Writes center out.
// Sequential over G=512 iterations; argmax with first-occurrence tie-break.
// ---------------------------------------------------------------------------
__global__ __launch_bounds__(1024) void fps_kernel(const float* __restrict__ xyz,
                                                   float* __restrict__ center_out) {
#pragma clang fp contract(off)
    __shared__ float sx[NPTS], sy[NPTS], sz[NPTS];
    __shared__ float red_v[2][16];
    __shared__ int   red_i[2][16];

    const int b   = blockIdx.x;
    const int tid = threadIdx.x;
    const int lane = tid & 63;
    const int wid  = tid >> 6;

    const float* xb = xyz + (size_t)b * NPTS * 3;
    // Stage xyz into LDS (SoA), fully coalesced flat read.
    for (int f = tid; f < NPTS * 3; f += 1024) {
        float v = xb[f];
        int p = f / 3;
        int c = f - 3 * p;
        if (c == 0) sx[p] = v; else if (c == 1) sy[p] = v; else sz[p] = v;
    }
    __syncthreads();

    // Register copies of this thread's 8 points (strided assignment).
    float px[8], py[8], pz[8], md[8];
#pragma unroll
    for (int j = 0; j < 8; ++j) {
        int p = tid + 1024 * j;
        px[j] = sx[p]; py[j] = sy[p]; pz[j] = sz[p];
        md[j] = 1e10f;
    }

    int far = 0;
    for (int g = 0; g < NG; ++g) {
        if (tid == 0) {
            center_out[(size_t)(b * NG + g) * 3 + 0] = sx[far];
            center_out[(size_t)(b * NG + g) * 3 + 1] = sy[far];
            center_out[(size_t)(b * NG + g) * 3 + 2] = sz[far];
        }
        const float cx = sx[far], cy = sy[far], cz = sz[far];

        // Update min_dist and local argmax (value, smallest index on ties).
        float bv = -1.0f;
        int   bi = 0;
#pragma unroll
        for (int j = 0; j < 8; ++j) {
            float dx = px[j] - cx;
            float dy = py[j] - cy;
            float dz = pz[j] - cz;
            float d  = (dx * dx + dy * dy) + dz * dz;   // matches ((d0+d1)+d2)
            float m  = fminf(md[j], d);
            md[j] = m;
            if (m > bv) { bv = m; bi = tid + 1024 * j; }  // strict > keeps earliest
        }
        // Wave (64-lane) argmax reduce with index tie-break.
#pragma unroll
        for (int s = 1; s < 64; s <<= 1) {
            float ov = __shfl_xor(bv, s);
            int   oi = __shfl_xor(bi, s);
            if (ov > bv || (ov == bv && oi < bi)) { bv = ov; bi = oi; }
        }
        const int par = g & 1;
        if (lane == 0) { red_v[par][wid] = bv; red_i[par][wid] = bi; }
        __syncthreads();
        // All threads redundantly combine the 16 wave results (broadcast reads).
        float fv = red_v[par][0];
        int   fi = red_i[par][0];
#pragma unroll
        for (int w = 1; w < 16; ++w) {
            float ov = red_v[par][w];
            int   oi = red_i[par][w];
            if (ov > fv || (ov == fv && oi < fi)) { fv = ov; fi = oi; }
        }
        far = fi;
    }
}

// ---------------------------------------------------------------------------
// Kernel B: exact 32-NN per center, output order = ascending (d, idx).
// One block (256 threads) per (b,g). 32 distances per thread in registers.
// Cached per-thread local min; only the extraction winner rescans.
// ---------------------------------------------------------------------------
__global__ __launch_bounds__(256) void knn_kernel(const float* __restrict__ xyz,
                                                  const float* __restrict__ center,
                                                  int* __restrict__ knn_idx) {
#pragma clang fp contract(off)
    __shared__ float red_v[2][4];
    __shared__ int   red_i[2][4];

    const int bg  = blockIdx.x;
    const int b   = bg >> 9;
    const int tid = threadIdx.x;
    const int lane = tid & 63;
    const int wid  = tid >> 6;

    const float cx = center[(size_t)bg * 3 + 0];
    const float cy = center[(size_t)bg * 3 + 1];
    const float cz = center[(size_t)bg * 3 + 2];
    const float q2 = (cx * cx + cy * cy) + cz * cz;   // plain add chain

    const float* xb = xyz + (size_t)b * NPTS * 3;

    float d[32];
#pragma unroll
    for (int j = 0; j < 32; ++j) {
        int p = tid + (j << 8);
        float rx = xb[p * 3 + 0];
        float ry = xb[p * 3 + 1];
        float rz = xb[p * 3 + 2];
        float r2 = (rx * rx + ry * ry) + rz * rz;     // plain add chain
        float dot = fmaf(cz, rz, fmaf(cy, ry, cx * rx)); // fma chain (sgemm-style)
        d[j] = (q2 + r2) - 2.0f * dot;
    }

    // Local min cache (value, global point index; ties -> smaller index).
    float lv = d[0];
    int   lp = tid;
#pragma unroll
    for (int j = 1; j < 32; ++j) {
        if (d[j] < lv) { lv = d[j]; lp = tid + (j << 8); }
    }

    int* out_idx = knn_idx + (size_t)bg * KM;
    for (int k = 0; k < KM; ++k) {
        float wv = lv;
        int   wp = lp;
#pragma unroll
        for (int s = 1; s < 64; s <<= 1) {
            float ov = __shfl_xor(wv, s);
            int   oi = __shfl_xor(wp, s);
            if (ov < wv || (ov == wv && oi < wp)) { wv = ov; wp = oi; }
        }
        const int par = k & 1;
        if (lane == 0) { red_v[par][wid] = wv; red_i[par][wid] = wp; }
        __syncthreads();
        float gv = red_v[par][0];
        int   gp = red_i[par][0];
#pragma unroll
        for (int w = 1; w < 4; ++w) {
            float ov = red_v[par][w];
            int   oi = red_i[par][w];
            if (ov < gv || (ov == gv && oi < gp)) { gv = ov; gp = oi; }
        }
        // Winner thread records, invalidates, and refreshes its local min.
        if ((gp & 255) == tid) {
            out_idx[k] = gp;
            const int jwin = gp >> 8;
#pragma unroll
            for (int j = 0; j < 32; ++j) {
                if (j == jwin) d[j] = __builtin_inff();
            }
            lv = __builtin_inff();
            lp = tid;
#pragma unroll
            for (int j = 0; j < 32; ++j) {
                if (d[j] < lv) { lv = d[j]; lp = tid + (j << 8); }
            }
        }
    }
}

// ---------------------------------------------------------------------------
// Kernel C: gather neighborhood (xyz - center) and feature rows (float4).
// One block (256 threads) per (b,g).
// ---------------------------------------------------------------------------
__global__ __launch_bounds__(256) void gather_kernel(const float* __restrict__ xyz,
                                                     const float* __restrict__ features,
                                                     const int* __restrict__ knn_idx,
                                                     const float* __restrict__ center,
                                                     float* __restrict__ out0,
                                                     float* __restrict__ out2) {
#pragma clang fp contract(off)
    __shared__ int   sidx[KM];
    __shared__ float sc[3];

    const int bg  = blockIdx.x;
    const int b   = bg >> 9;
    const int tid = threadIdx.x;

    if (tid < KM) sidx[tid] = knn_idx[(size_t)bg * KM + tid];
    if (tid < 3)  sc[tid]   = center[(size_t)bg * 3 + tid];
    __syncthreads();

    // neighborhood: 32 x 3 = 96 floats
    if (tid < 96) {
        int m = tid / 3;
        int c = tid - 3 * m;
        int p = sidx[m];
        float v = xyz[((size_t)b * NPTS + p) * 3 + c] - sc[c];
        out0[((size_t)bg * KM + m) * 3 + c] = v;
    }

    // features: 32 rows x 384 floats = 3072 float4, 12 per thread
    const float4* fb = (const float4*)(features + (size_t)b * NPTS * FEATC);
    float4*       ob = (float4*)(out2 + (size_t)bg * KM * FEATC);
#pragma unroll
    for (int r = 0; r < 12; ++r) {
        int flat = tid + (r << 8);          // 0..3071
        int m  = flat / 96;
        int c4 = flat - 96 * m;
        float4 v = fb[(size_t)sidx[m] * 96 + c4];
        ob[(size_t)m * 96 + c4] = v;
    }
}

extern "C" void kernel_launch(void* const* d_in, const int* in_sizes, int n_in,
                              void* d_out, int out_size, void* d_ws, size_t ws_size,
                              hipStream_t stream) {
    const float* xyz      = (const float*)d_in[0];
    const float* features = (const float*)d_in[1];
    float* out  = (float*)d_out;
    float* out0 = out + OUT0_OFF;   // neighborhood
    float* out1 = out + OUT1_OFF;   // center
    float* out2 = out + OUT2_OFF;   // feature_group

    int* knn_idx = (int*)d_ws;      // 16*512*32 ints = 1 MiB

    fps_kernel<<<BATCH, 1024, 0, stream>>>(xyz, out1);
    knn_kernel<<<BATCH * NG, 256, 0, stream>>>(xyz, out1, knn_idx);
    gather_kernel<<<BATCH * NG, 256, 0, stream>>>(xyz, features, knn_idx, out1,
                                                  out0, out2);
}

// Round 2
// 941.822 us; speedup vs baseline: 1.8161x; 1.8161x over previous
//
#include <hip/hip_runtime.h>
#include <math.h>

// Problem constants (match reference)
#define BATCH 16
#define NPTS  8192
#define FEATC 384
#define NG    512
#define KM    32

// d_out layout (flat float32, concatenated in return order)
#define OUT0_OFF 0                              // neighborhood [16,512,32,3]
#define OUT1_OFF (BATCH * NG * KM * 3)          // center       [16,512,3]
#define OUT2_OFF (OUT1_OFF + BATCH * NG * 3)    // feature_group[16,512,32,384]

// Disable FP contraction so mul/add rounding matches the numpy reference.
#pragma clang fp contract(off)

typedef float f32x2 __attribute__((ext_vector_type(2)));

// ---------------------------------------------------------------------------
// DPP helpers: fast in-VALU wave64 reductions.
// quad_perm xor1 (0xB1), xor2 (0x4E); row_ror:4 (0x124), row_ror:8 (0x128)
// give every lane its 16-row reduction; shfl_xor 16/32 finish the wave.
// ---------------------------------------------------------------------------
template <int CTRL>
__device__ __forceinline__ int dpp_i(int x) {
    return __builtin_amdgcn_update_dpp(0, x, CTRL, 0xF, 0xF, false);
}

__device__ __forceinline__ float wave_max_f32(float v) {
    float t;
    t = __int_as_float(dpp_i<0xB1>(__float_as_int(v)));  v = fmaxf(v, t);
    t = __int_as_float(dpp_i<0x4E>(__float_as_int(v)));  v = fmaxf(v, t);
    t = __int_as_float(dpp_i<0x124>(__float_as_int(v))); v = fmaxf(v, t);
    t = __int_as_float(dpp_i<0x128>(__float_as_int(v))); v = fmaxf(v, t);
    v = fmaxf(v, __shfl_xor(v, 16));
    v = fmaxf(v, __shfl_xor(v, 32));
    return v;
}

__device__ __forceinline__ unsigned wave_min_u32(unsigned v) {
    unsigned t;
    t = (unsigned)dpp_i<0xB1>((int)v);  v = t < v ? t : v;
    t = (unsigned)dpp_i<0x4E>((int)v);  v = t < v ? t : v;
    t = (unsigned)dpp_i<0x124>((int)v); v = t < v ? t : v;
    t = (unsigned)dpp_i<0x128>((int)v); v = t < v ? t : v;
    t = (unsigned)__shfl_xor((int)v, 16); v = t < v ? t : v;
    t = (unsigned)__shfl_xor((int)v, 32); v = t < v ? t : v;
    return v;
}

__device__ __forceinline__ unsigned long long wave_min_u64(unsigned long long k) {
#define U64_DPP_STEP(C)                                                        \
    {                                                                          \
        unsigned lo = (unsigned)dpp_i<C>((int)(unsigned)k);                    \
        unsigned hi = (unsigned)dpp_i<C>((int)(unsigned)(k >> 32));            \
        unsigned long long o = ((unsigned long long)hi << 32) | lo;            \
        if (o < k) k = o;                                                      \
    }
    U64_DPP_STEP(0xB1)
    U64_DPP_STEP(0x4E)
    U64_DPP_STEP(0x124)
    U64_DPP_STEP(0x128)
#undef U64_DPP_STEP
    {
        unsigned long long o = __shfl_xor(k, 16);
        if (o < k) k = o;
    }
    {
        unsigned long long o = __shfl_xor(k, 32);
        if (o < k) k = o;
    }
    return k;
}

// Tree-min over a 32-entry register array (static indices after inlining).
__device__ __forceinline__ unsigned long long min32_u64(const unsigned long long* k) {
    unsigned long long t16[16];
#pragma unroll
    for (int i = 0; i < 16; ++i) t16[i] = k[i] < k[i + 16] ? k[i] : k[i + 16];
    unsigned long long t8[8];
#pragma unroll
    for (int i = 0; i < 8; ++i) t8[i] = t16[i] < t16[i + 8] ? t16[i] : t16[i + 8];
    unsigned long long t4[4];
#pragma unroll
    for (int i = 0; i < 4; ++i) t4[i] = t8[i] < t8[i + 4] ? t8[i] : t8[i + 4];
    unsigned long long a = t4[0] < t4[2] ? t4[0] : t4[2];
    unsigned long long b = t4[1] < t4[3] ? t4[1] : t4[3];
    return a < b ? a : b;
}

// ---------------------------------------------------------------------------
// Kernel A: farthest point sampling. One block (512 thr) per batch.
// Packed-fp32 distance updates; value-max (phase A) then min-index among
// exact matches (phase B). 2 barriers / iteration, parity double-buffered.
// ---------------------------------------------------------------------------
__global__ __launch_bounds__(512) void fps_kernel(const float* __restrict__ xyz,
                                                  float* __restrict__ center_out) {
#pragma clang fp contract(off)
    __shared__ float sx[NPTS], sy[NPTS], sz[NPTS];
    __shared__ float    swmax[2][8];
    __shared__ unsigned swidx[2][8];

    const int b    = blockIdx.x;
    const int tid  = threadIdx.x;
    const int lane = tid & 63;
    const int wid  = tid >> 6;          // 8 waves

    const float* xb = xyz + (size_t)b * NPTS * 3;
    for (int f = tid; f < NPTS * 3; f += 512) {
        float v = xb[f];
        int p = f / 3;
        int c = f - 3 * p;
        if (c == 0) sx[p] = v; else if (c == 1) sy[p] = v; else sz[p] = v;
    }
    __syncthreads();

    // 16 points per thread as 8 packed pairs: slot j holds pts tid+1024j, +512.
    f32x2 X[8], Y[8], Z[8], MD[8];
#pragma unroll
    for (int j = 0; j < 8; ++j) {
        int p0 = tid + 1024 * j;
        X[j]  = (f32x2){sx[p0], sx[p0 + 512]};
        Y[j]  = (f32x2){sy[p0], sy[p0 + 512]};
        Z[j]  = (f32x2){sz[p0], sz[p0 + 512]};
        MD[j] = (f32x2){1e10f, 1e10f};
    }

    int far = 0;
    for (int g = 0; g < NG; ++g) {
        if (tid == 0) {
            center_out[(size_t)(b * NG + g) * 3 + 0] = sx[far];
            center_out[(size_t)(b * NG + g) * 3 + 1] = sy[far];
            center_out[(size_t)(b * NG + g) * 3 + 2] = sz[far];
        }
        const float cx = sx[far], cy = sy[far], cz = sz[far];
        const f32x2 cx2 = (f32x2){cx, cx};
        const f32x2 cy2 = (f32x2){cy, cy};
        const f32x2 cz2 = (f32x2){cz, cz};

        // Update min-dist (packed, exact: (dx*dx + dy*dy) + dz*dz, no fma).
#pragma unroll
        for (int j = 0; j < 8; ++j) {
            f32x2 dx = X[j] - cx2;
            f32x2 dy = Y[j] - cy2;
            f32x2 dz = Z[j] - cz2;
            f32x2 d  = (dx * dx + dy * dy) + dz * dz;
            MD[j] = __builtin_elementwise_min(MD[j], d);
        }
        // Phase A: max VALUE only (pure v_max trees).
        f32x2 a0 = __builtin_elementwise_max(MD[0], MD[1]);
        f32x2 a1 = __builtin_elementwise_max(MD[2], MD[3]);
        f32x2 a2 = __builtin_elementwise_max(MD[4], MD[5]);
        f32x2 a3 = __builtin_elementwise_max(MD[6], MD[7]);
        f32x2 b0 = __builtin_elementwise_max(a0, a1);
        f32x2 b1 = __builtin_elementwise_max(a2, a3);
        f32x2 c0 = __builtin_elementwise_max(b0, b1);
        float lmax = fmaxf(c0.x, c0.y);
        float wmax = wave_max_f32(lmax);

        const int par = g & 1;
        if (lane == 0) swmax[par][wid] = wmax;
        __syncthreads();
        float t0 = fmaxf(swmax[par][0], swmax[par][1]);
        float t1 = fmaxf(swmax[par][2], swmax[par][3]);
        float t2 = fmaxf(swmax[par][4], swmax[par][5]);
        float t3 = fmaxf(swmax[par][6], swmax[par][7]);
        const float gmax = fmaxf(fmaxf(t0, t1), fmaxf(t2, t3));

        // Phase B: min global index among exact matches. Only the wave(s)
        // containing the max pay the scan (wave-uniform ballot guard).
        unsigned cand = 0xFFFFFFFFu;
        if (__ballot(lmax == gmax)) {
            if (lmax == gmax) {
#pragma unroll
                for (int j = 7; j >= 0; --j) {
                    if (MD[j].y == gmax) cand = (unsigned)(tid + 1024 * j + 512);
                    if (MD[j].x == gmax) cand = (unsigned)(tid + 1024 * j);
                }
            }
            cand = wave_min_u32(cand);
        }
        if (lane == 0) swidx[par][wid] = cand;
        __syncthreads();
        unsigned m0 = swidx[par][0] < swidx[par][1] ? swidx[par][0] : swidx[par][1];
        unsigned m1 = swidx[par][2] < swidx[par][3] ? swidx[par][2] : swidx[par][3];
        unsigned m2 = swidx[par][4] < swidx[par][5] ? swidx[par][4] : swidx[par][5];
        unsigned m3 = swidx[par][6] < swidx[par][7] ? swidx[par][6] : swidx[par][7];
        unsigned ma = m0 < m1 ? m0 : m1;
        unsigned mb = m2 < m3 ? m2 : m3;
        far = (int)(ma < mb ? ma : mb);
    }
}

// ---------------------------------------------------------------------------
// Kernel B: exact 32-NN per center, ascending (d, idx) order via packed
// sortable u64 keys (ties exact by construction). One block (256 thr)/(b,g).
// ---------------------------------------------------------------------------
__global__ __launch_bounds__(256) void knn_kernel(const float* __restrict__ xyz,
                                                  const float* __restrict__ center,
                                                  int* __restrict__ knn_idx) {
#pragma clang fp contract(off)
    __shared__ unsigned long long skey[2][4];

    const int bg   = blockIdx.x;
    const int b    = bg >> 9;
    const int tid  = threadIdx.x;
    const int lane = tid & 63;
    const int wid  = tid >> 6;

    const float cx = center[(size_t)bg * 3 + 0];
    const float cy = center[(size_t)bg * 3 + 1];
    const float cz = center[(size_t)bg * 3 + 2];
    const float q2 = (cx * cx + cy * cy) + cz * cz;   // plain add chain

    const float* xb = xyz + (size_t)b * NPTS * 3;

    unsigned long long k[32];
#pragma unroll
    for (int j = 0; j < 32; ++j) {
        int p = tid + (j << 8);
        float rx = xb[p * 3 + 0];
        float ry = xb[p * 3 + 1];
        float rz = xb[p * 3 + 2];
        float r2 = (rx * rx + ry * ry) + rz * rz;         // plain add chain
        float dot = fmaf(cz, rz, fmaf(cy, ry, cx * rx));  // fma chain (sgemm-style)
        float d = (q2 + r2) - 2.0f * dot;                 // identical to round 1
        unsigned u = __float_as_uint(d);
        u ^= ((unsigned)((int)u >> 31)) | 0x80000000u;    // sortable float
        k[j] = ((unsigned long long)u << 32) | (unsigned)p;
    }

    unsigned long long lv = min32_u64(k);

    int* out_idx = knn_idx + (size_t)bg * KM;
    for (int kk = 0; kk < KM; ++kk) {
        unsigned long long w = wave_min_u64(lv);
        const int par = kk & 1;
        if (lane == 0) skey[par][wid] = w;
        __syncthreads();
        unsigned long long a = skey[par][0] < skey[par][1] ? skey[par][0] : skey[par][1];
        unsigned long long c = skey[par][2] < skey[par][3] ? skey[par][2] : skey[par][3];
        unsigned long long gk = a < c ? a : c;
        const unsigned pt = (unsigned)gk;                 // low 32 = point idx
        if ((pt & 255u) == (unsigned)tid) {
            out_idx[kk] = (int)pt;
            const unsigned jw = pt >> 8;
#pragma unroll
            for (int j = 0; j < 32; ++j) {
                if ((unsigned)j == jw) k[j] = ~0ULL;
            }
            lv = min32_u64(k);
        }
    }
}

// ---------------------------------------------------------------------------
// Kernel C: gather neighborhood (xyz - center) and feature rows (float4).
// One block (256 threads) per (b,g).
// ---------------------------------------------------------------------------
__global__ __launch_bounds__(256) void gather_kernel(const float* __restrict__ xyz,
                                                     const float* __restrict__ features,
                                                     const int* __restrict__ knn_idx,
                                                     const float* __restrict__ center,
                                                     float* __restrict__ out0,
                                                     float* __restrict__ out2) {
#pragma clang fp contract(off)
    __shared__ int   sidx[KM];
    __shared__ float sc[3];

    const int bg  = blockIdx.x;
    const int b   = bg >> 9;
    const int tid = threadIdx.x;

    if (tid < KM) sidx[tid] = knn_idx[(size_t)bg * KM + tid];
    if (tid < 3)  sc[tid]   = center[(size_t)bg * 3 + tid];
    __syncthreads();

    // neighborhood: 32 x 3 = 96 floats
    if (tid < 96) {
        int m = tid / 3;
        int c = tid - 3 * m;
        int p = sidx[m];
        float v = xyz[((size_t)b * NPTS + p) * 3 + c] - sc[c];
        out0[((size_t)bg * KM + m) * 3 + c] = v;
    }

    // features: 32 rows x 384 floats = 3072 float4, 12 per thread
    const float4* fb = (const float4*)(features + (size_t)b * NPTS * FEATC);
    float4*       ob = (float4*)(out2 + (size_t)bg * KM * FEATC);
#pragma unroll
    for (int r = 0; r < 12; ++r) {
        int flat = tid + (r << 8);          // 0..3071
        int m  = flat / 96;
        int c4 = flat - 96 * m;
        float4 v = fb[(size_t)sidx[m] * 96 + c4];
        ob[(size_t)m * 96 + c4] = v;
    }
}

extern "C" void kernel_launch(void* const* d_in, const int* in_sizes, int n_in,
                              void* d_out, int out_size, void* d_ws, size_t ws_size,
                              hipStream_t stream) {
    const float* xyz      = (const float*)d_in[0];
    const float* features = (const float*)d_in[1];
    float* out  = (float*)d_out;
    float* out0 = out + OUT0_OFF;   // neighborhood
    float* out1 = out + OUT1_OFF;   // center
    float* out2 = out + OUT2_OFF;   // feature_group

    int* knn_idx = (int*)d_ws;      // 16*512*32 ints = 1 MiB

    fps_kernel<<<BATCH, 512, 0, stream>>>(xyz, out1);
    knn_kernel<<<BATCH * NG, 256, 0, stream>>>(xyz, out1, knn_idx);
    gather_kernel<<<BATCH * NG, 256, 0, stream>>>(xyz, features, knn_idx, out1,
                                                  out0, out2);
}

// Round 3
// 882.050 us; speedup vs baseline: 1.9392x; 1.0678x over previous
//
#include <hip/hip_runtime.h>
#include <math.h>

// Problem constants (match reference)
#define BATCH 16
#define NPTS  8192
#define FEATC 384
#define NG    512
#define KM    32

// d_out layout (flat float32, concatenated in return order)
#define OUT0_OFF 0                              // neighborhood [16,512,32,3]
#define OUT1_OFF (BATCH * NG * KM * 3)          // center       [16,512,3]
#define OUT2_OFF (OUT1_OFF + BATCH * NG * 3)    // feature_group[16,512,32,384]

// Disable FP contraction so mul/add rounding matches the numpy reference.
#pragma clang fp contract(off)

typedef float f32x2 __attribute__((ext_vector_type(2)));

// ---------------------------------------------------------------------------
// DPP wave64 reductions, all-VALU (no LDS/bpermute on the chain).
// row_shr:1/2/4/8 fold each 16-lane row into its top lane; row_bcast:15 and
// row_bcast:31 fold rows together. Result valid in lane 63 (rocPRIM pattern).
// bound_ctrl=false + old=src => disabled lanes keep their own value (identity
// for both min and max).
// ---------------------------------------------------------------------------
template <int CTRL>
__device__ __forceinline__ unsigned long long dpp_u64(unsigned long long k) {
    unsigned lo = (unsigned)k, hi = (unsigned)(k >> 32);
    lo = (unsigned)__builtin_amdgcn_update_dpp((int)lo, (int)lo, CTRL, 0xF, 0xF, false);
    hi = (unsigned)__builtin_amdgcn_update_dpp((int)hi, (int)hi, CTRL, 0xF, 0xF, false);
    return ((unsigned long long)hi << 32) | lo;
}

__device__ __forceinline__ unsigned long long wave_max_u64(unsigned long long k) {
    unsigned long long o;
    o = dpp_u64<0x111>(k); if (o > k) k = o;   // row_shr:1
    o = dpp_u64<0x112>(k); if (o > k) k = o;   // row_shr:2
    o = dpp_u64<0x114>(k); if (o > k) k = o;   // row_shr:4
    o = dpp_u64<0x118>(k); if (o > k) k = o;   // row_shr:8
    o = dpp_u64<0x142>(k); if (o > k) k = o;   // row_bcast:15
    o = dpp_u64<0x143>(k); if (o > k) k = o;   // row_bcast:31
    return k;                                   // lane 63 holds the max
}

__device__ __forceinline__ unsigned long long wave_min_u64(unsigned long long k) {
    unsigned long long o;
    o = dpp_u64<0x111>(k); if (o < k) k = o;
    o = dpp_u64<0x112>(k); if (o < k) k = o;
    o = dpp_u64<0x114>(k); if (o < k) k = o;
    o = dpp_u64<0x118>(k); if (o < k) k = o;
    o = dpp_u64<0x142>(k); if (o < k) k = o;
    o = dpp_u64<0x143>(k); if (o < k) k = o;
    return k;                                   // lane 63 holds the min
}

// Tree-min over a 32-entry register array (static indices after inlining).
__device__ __forceinline__ unsigned long long min32_u64(const unsigned long long* k) {
    unsigned long long t16[16];
#pragma unroll
    for (int i = 0; i < 16; ++i) t16[i] = k[i] < k[i + 16] ? k[i] : k[i + 16];
    unsigned long long t8[8];
#pragma unroll
    for (int i = 0; i < 8; ++i) t8[i] = t16[i] < t16[i + 8] ? t16[i] : t16[i + 8];
    unsigned long long t4[4];
#pragma unroll
    for (int i = 0; i < 4; ++i) t4[i] = t8[i] < t8[i + 4] ? t8[i] : t8[i + 4];
    unsigned long long a = t4[0] < t4[2] ? t4[0] : t4[2];
    unsigned long long b = t4[1] < t4[3] ? t4[1] : t4[3];
    return a < b ? a : b;
}

// ---------------------------------------------------------------------------
// Kernel A: farthest point sampling. One block (512 thr, 8 waves) per batch.
// Single barrier per iteration: per-lane (max dist, min idx) folded into one
// sortable u64 key (dist bits are non-negative floats => bit order = value
// order; low word = ~idx so u64-max gives min index on exact ties).
// No global stores inside the loop (avoids vmcnt(0) drain at each barrier):
// chosen indices go to LDS, centers written coalesced at the end.
// ---------------------------------------------------------------------------
__global__ __launch_bounds__(512) void fps_kernel(const float* __restrict__ xyz,
                                                  float* __restrict__ center_out) {
#pragma clang fp contract(off)
    __shared__ float sx[NPTS], sy[NPTS], sz[NPTS];
    __shared__ unsigned long long sk[2][8];
    __shared__ int sfar[NG];

    const int b    = blockIdx.x;
    const int tid  = threadIdx.x;
    const int lane = tid & 63;
    const int wid  = tid >> 6;          // 8 waves

    const float* xb = xyz + (size_t)b * NPTS * 3;
    for (int f = tid; f < NPTS * 3; f += 512) {
        float v = xb[f];
        int p = f / 3;
        int c = f - 3 * p;
        if (c == 0) sx[p] = v; else if (c == 1) sy[p] = v; else sz[p] = v;
    }
    __syncthreads();

    // 16 points per thread as 8 packed pairs: slot j holds pts tid+1024j, +512.
    f32x2 X[8], Y[8], Z[8], MD[8];
#pragma unroll
    for (int j = 0; j < 8; ++j) {
        int p0 = tid + 1024 * j;
        X[j]  = (f32x2){sx[p0], sx[p0 + 512]};
        Y[j]  = (f32x2){sy[p0], sy[p0 + 512]};
        Z[j]  = (f32x2){sz[p0], sz[p0 + 512]};
        MD[j] = (f32x2){1e10f, 1e10f};
    }

    int far = 0;
    for (int g = 0; g < NG; ++g) {
        if (tid == g) sfar[g] = far;    // record g-th center index (LDS only)
        const float cx = sx[far], cy = sy[far], cz = sz[far];
        const f32x2 cx2 = (f32x2){cx, cx};
        const f32x2 cy2 = (f32x2){cy, cy};
        const f32x2 cz2 = (f32x2){cz, cz};

        // Update min-dist (packed, exact: (dx*dx + dy*dy) + dz*dz, no fma).
#pragma unroll
        for (int j = 0; j < 8; ++j) {
            f32x2 dx = X[j] - cx2;
            f32x2 dy = Y[j] - cy2;
            f32x2 dz = Z[j] - cz2;
            f32x2 d  = (dx * dx + dy * dy) + dz * dz;
            MD[j] = __builtin_elementwise_min(MD[j], d);
        }
        // Per-lane max value (pure v_pk_max tree).
        f32x2 a0 = __builtin_elementwise_max(MD[0], MD[1]);
        f32x2 a1 = __builtin_elementwise_max(MD[2], MD[3]);
        f32x2 a2 = __builtin_elementwise_max(MD[4], MD[5]);
        f32x2 a3 = __builtin_elementwise_max(MD[6], MD[7]);
        f32x2 b0 = __builtin_elementwise_max(a0, a1);
        f32x2 b1 = __builtin_elementwise_max(a2, a3);
        f32x2 c0 = __builtin_elementwise_max(b0, b1);
        float lmax = fmaxf(c0.x, c0.y);

        // Smallest owned index attaining lmax (two short overwrite chains).
        unsigned candX = 0xFFFFFFFFu, candY = 0xFFFFFFFFu;
#pragma unroll
        for (int j = 7; j >= 0; --j) {
            if (MD[j].y == lmax) candY = (unsigned)(tid + 1024 * j + 512);
            if (MD[j].x == lmax) candX = (unsigned)(tid + 1024 * j);
        }
        unsigned cand = candX < candY ? candX : candY;

        unsigned long long key =
            ((unsigned long long)__float_as_uint(lmax) << 32) | (unsigned)(~cand);
        key = wave_max_u64(key);        // lane 63 valid

        const int par = g & 1;
        if (lane == 63) sk[par][wid] = key;
        __syncthreads();

        unsigned long long m0 = sk[par][0] > sk[par][1] ? sk[par][0] : sk[par][1];
        unsigned long long m1 = sk[par][2] > sk[par][3] ? sk[par][2] : sk[par][3];
        unsigned long long m2 = sk[par][4] > sk[par][5] ? sk[par][4] : sk[par][5];
        unsigned long long m3 = sk[par][6] > sk[par][7] ? sk[par][6] : sk[par][7];
        unsigned long long ma = m0 > m1 ? m0 : m1;
        unsigned long long mb = m2 > m3 ? m2 : m3;
        unsigned long long gk = ma > mb ? ma : mb;
        far = (int)(~(unsigned)gk);     // low word = ~idx
    }
    __syncthreads();
    // Coalesced-ish center write-out, one g per thread.
    if (tid < NG) {
        int p = sfar[tid];
        size_t o = ((size_t)b * NG + tid) * 3;
        center_out[o + 0] = sx[p];
        center_out[o + 1] = sy[p];
        center_out[o + 2] = sz[p];
    }
}

// ---------------------------------------------------------------------------
// Kernel B: exact 32-NN per center, ascending (d, idx) order via packed
// sortable u64 keys. One block (256 thr) per (b,g). DPP wave min-reduce,
// results staged in LDS (no global store inside the round loop).
// ---------------------------------------------------------------------------
__global__ __launch_bounds__(256) void knn_kernel(const float* __restrict__ xyz,
                                                  const float* __restrict__ center,
                                                  int* __restrict__ knn_idx) {
#pragma clang fp contract(off)
    __shared__ unsigned long long skey[2][4];
    __shared__ int sres[KM];

    const int bg   = blockIdx.x;
    const int b    = bg >> 9;
    const int tid  = threadIdx.x;
    const int lane = tid & 63;
    const int wid  = tid >> 6;

    const float cx = center[(size_t)bg * 3 + 0];
    const float cy = center[(size_t)bg * 3 + 1];
    const float cz = center[(size_t)bg * 3 + 2];
    const float q2 = (cx * cx + cy * cy) + cz * cz;   // plain add chain

    const float* xb = xyz + (size_t)b * NPTS * 3;

    unsigned long long k[32];
#pragma unroll
    for (int j = 0; j < 32; ++j) {
        int p = tid + (j << 8);
        float rx = xb[p * 3 + 0];
        float ry = xb[p * 3 + 1];
        float rz = xb[p * 3 + 2];
        float r2 = (rx * rx + ry * ry) + rz * rz;         // plain add chain
        float dot = fmaf(cz, rz, fmaf(cy, ry, cx * rx));  // fma chain (sgemm-style)
        float d = (q2 + r2) - 2.0f * dot;                 // identical to round 1
        unsigned u = __float_as_uint(d);
        u ^= ((unsigned)((int)u >> 31)) | 0x80000000u;    // sortable float
        k[j] = ((unsigned long long)u << 32) | (unsigned)p;
    }

    unsigned long long lv = min32_u64(k);

    for (int kk = 0; kk < KM; ++kk) {
        unsigned long long w = wave_min_u64(lv);          // lane 63 valid
        const int par = kk & 1;
        if (lane == 63) skey[par][wid] = w;
        __syncthreads();
        unsigned long long a = skey[par][0] < skey[par][1] ? skey[par][0] : skey[par][1];
        unsigned long long c = skey[par][2] < skey[par][3] ? skey[par][2] : skey[par][3];
        unsigned long long gk = a < c ? a : c;
        const unsigned pt = (unsigned)gk;                 // low 32 = point idx
        if ((pt & 255u) == (unsigned)tid) {
            sres[kk] = (int)pt;                           // LDS, not global
            const unsigned jw = pt >> 8;
#pragma unroll
            for (int j = 0; j < 32; ++j) {
                if ((unsigned)j == jw) k[j] = ~0ULL;
            }
            lv = min32_u64(k);
        }
    }
    __syncthreads();
    if (tid < KM) knn_idx[(size_t)bg * KM + tid] = sres[tid];
}

// ---------------------------------------------------------------------------
// Kernel C: gather neighborhood (xyz - center) and feature rows (float4).
// One block (256 threads) per (b,g).
// ---------------------------------------------------------------------------
__global__ __launch_bounds__(256) void gather_kernel(const float* __restrict__ xyz,
                                                     const float* __restrict__ features,
                                                     const int* __restrict__ knn_idx,
                                                     const float* __restrict__ center,
                                                     float* __restrict__ out0,
                                                     float* __restrict__ out2) {
#pragma clang fp contract(off)
    __shared__ int   sidx[KM];
    __shared__ float sc[3];

    const int bg  = blockIdx.x;
    const int b   = bg >> 9;
    const int tid = threadIdx.x;

    if (tid < KM) sidx[tid] = knn_idx[(size_t)bg * KM + tid];
    if (tid < 3)  sc[tid]   = center[(size_t)bg * 3 + tid];
    __syncthreads();

    // neighborhood: 32 x 3 = 96 floats
    if (tid < 96) {
        int m = tid / 3;
        int c = tid - 3 * m;
        int p = sidx[m];
        float v = xyz[((size_t)b * NPTS + p) * 3 + c] - sc[c];
        out0[((size_t)bg * KM + m) * 3 + c] = v;
    }

    // features: 32 rows x 384 floats = 3072 float4, 12 per thread
    const float4* fb = (const float4*)(features + (size_t)b * NPTS * FEATC);
    float4*       ob = (float4*)(out2 + (size_t)bg * KM * FEATC);
#pragma unroll
    for (int r = 0; r < 12; ++r) {
        int flat = tid + (r << 8);          // 0..3071
        int m  = flat / 96;
        int c4 = flat - 96 * m;
        float4 v = fb[(size_t)sidx[m] * 96 + c4];
        ob[(size_t)m * 96 + c4] = v;
    }
}

extern "C" void kernel_launch(void* const* d_in, const int* in_sizes, int n_in,
                              void* d_out, int out_size, void* d_ws, size_t ws_size,
                              hipStream_t stream) {
    const float* xyz      = (const float*)d_in[0];
    const float* features = (const float*)d_in[1];
    float* out  = (float*)d_out;
    float* out0 = out + OUT0_OFF;   // neighborhood
    float* out1 = out + OUT1_OFF;   // center
    float* out2 = out + OUT2_OFF;   // feature_group

    int* knn_idx = (int*)d_ws;      // 16*512*32 ints = 1 MiB

    fps_kernel<<<BATCH, 512, 0, stream>>>(xyz, out1);
    knn_kernel<<<BATCH * NG, 256, 0, stream>>>(xyz, out1, knn_idx);
    gather_kernel<<<BATCH * NG, 256, 0, stream>>>(xyz, features, knn_idx, out1,
                                                  out0, out2);
}

// Round 4
// 700.098 us; speedup vs baseline: 2.4432x; 1.2599x over previous
//
#include <hip/hip_runtime.h>
#include <math.h>

// Problem constants (match reference)
#define BATCH 16
#define NPTS  8192
#define FEATC 384
#define NG    512
#define KM    32

// d_out layout (flat float32, concatenated in return order)
#define OUT0_OFF 0                              // neighborhood [16,512,32,3]
#define OUT1_OFF (BATCH * NG * KM * 3)          // center       [16,512,3]
#define OUT2_OFF (OUT1_OFF + BATCH * NG * 3)    // feature_group[16,512,32,384]

// Disable FP contraction so mul/add rounding matches the numpy reference.
#pragma clang fp contract(off)

typedef float f32x2 __attribute__((ext_vector_type(2)));

// ---------------------------------------------------------------------------
// DPP wave64 reductions, all-VALU. row_shr:1/2/4/8 fold each 16-lane row into
// its top lane; row_bcast:15/31 fold rows. Result valid in lane 63.
// ---------------------------------------------------------------------------
template <int CTRL>
__device__ __forceinline__ unsigned long long dpp_u64(unsigned long long k) {
    unsigned lo = (unsigned)k, hi = (unsigned)(k >> 32);
    lo = (unsigned)__builtin_amdgcn_update_dpp((int)lo, (int)lo, CTRL, 0xF, 0xF, false);
    hi = (unsigned)__builtin_amdgcn_update_dpp((int)hi, (int)hi, CTRL, 0xF, 0xF, false);
    return ((unsigned long long)hi << 32) | lo;
}

__device__ __forceinline__ unsigned long long wave_max_u64(unsigned long long k) {
    unsigned long long o;
    o = dpp_u64<0x111>(k); if (o > k) k = o;   // row_shr:1
    o = dpp_u64<0x112>(k); if (o > k) k = o;   // row_shr:2
    o = dpp_u64<0x114>(k); if (o > k) k = o;   // row_shr:4
    o = dpp_u64<0x118>(k); if (o > k) k = o;   // row_shr:8
    o = dpp_u64<0x142>(k); if (o > k) k = o;   // row_bcast:15
    o = dpp_u64<0x143>(k); if (o > k) k = o;   // row_bcast:31
    return k;
}

__device__ __forceinline__ unsigned long long wave_min_u64(unsigned long long k) {
    unsigned long long o;
    o = dpp_u64<0x111>(k); if (o < k) k = o;
    o = dpp_u64<0x112>(k); if (o < k) k = o;
    o = dpp_u64<0x114>(k); if (o < k) k = o;
    o = dpp_u64<0x118>(k); if (o < k) k = o;
    o = dpp_u64<0x142>(k); if (o < k) k = o;
    o = dpp_u64<0x143>(k); if (o < k) k = o;
    return k;
}

// Tree-min over a 16-entry register array (static indices after inlining).
__device__ __forceinline__ unsigned long long min16_u64(const unsigned long long* k) {
    unsigned long long t8[8];
#pragma unroll
    for (int i = 0; i < 8; ++i) t8[i] = k[i] < k[i + 8] ? k[i] : k[i + 8];
    unsigned long long t4[4];
#pragma unroll
    for (int i = 0; i < 4; ++i) t4[i] = t8[i] < t8[i + 4] ? t8[i] : t8[i + 4];
    unsigned long long a = t4[0] < t4[2] ? t4[0] : t4[2];
    unsigned long long b = t4[1] < t4[3] ? t4[1] : t4[3];
    return a < b ? a : b;
}

// ---------------------------------------------------------------------------
// Init kernel: zero the per-batch progress counters (d_ws content is
// arbitrary on every call; stream order guarantees this completes first).
// ---------------------------------------------------------------------------
__global__ void init_progress(int* progress) {
    if (threadIdx.x < BATCH)
        __hip_atomic_store(&progress[threadIdx.x], 0,
                           __ATOMIC_RELAXED, __HIP_MEMORY_SCOPE_AGENT);
}

// ---------------------------------------------------------------------------
// Merged producer-consumer kernel.
//   blocks [0,16):            FPS producer, one per batch (512 thr, 8 waves).
//   blocks [16, 16+8192):     consumer per (g,b) (g-major order = production
//                             order), does exact 32-NN + gather + subtract.
// Producers never wait => no deadlock. Consumers acquire-spin on progress[b]
// (published every 8 centers via release store; centers via relaxed AGENT
// atomic stores so they are device-visible cross-XCD).
// ---------------------------------------------------------------------------
__global__ __launch_bounds__(512) void group_kernel(const float* __restrict__ xyz,
                                                    const float* __restrict__ features,
                                                    float* __restrict__ out0,
                                                    float* __restrict__ out1,
                                                    float* __restrict__ out2,
                                                    int* __restrict__ progress) {
#pragma clang fp contract(off)
    __shared__ unsigned long long sk[2][8];   // per-wave reduce slots
    __shared__ int   sidx[KM];                // consumer: knn result indices
    __shared__ float sc[3];                   // consumer: center coords

    const int tid  = threadIdx.x;
    const int lane = tid & 63;
    const int wid  = tid >> 6;                // 8 waves

    if (blockIdx.x < BATCH) {
        // ================= FPS producer =================
        const int b = blockIdx.x;
        const float* xb = xyz + (size_t)b * NPTS * 3;
        unsigned* co = (unsigned*)out1 + (size_t)b * NG * 3;

        // 16 points per thread as 8 packed pairs (direct global load, one-time).
        f32x2 X[8], Y[8], Z[8], MD[8];
#pragma unroll
        for (int j = 0; j < 8; ++j) {
            int p0 = tid + 1024 * j;
            int p1 = p0 + 512;
            X[j]  = (f32x2){xb[p0 * 3 + 0], xb[p1 * 3 + 0]};
            Y[j]  = (f32x2){xb[p0 * 3 + 1], xb[p1 * 3 + 1]};
            Z[j]  = (f32x2){xb[p0 * 3 + 2], xb[p1 * 3 + 2]};
            MD[j] = (f32x2){1e10f, 1e10f};
        }

        int far = 0;
        for (int g = 0; g < NG; ++g) {
            const float cx = xb[far * 3 + 0];
            const float cy = xb[far * 3 + 1];
            const float cz = xb[far * 3 + 2];
            if (tid == 0) {
                // Publish center g (device-scope visible).
                __hip_atomic_store(co + g * 3 + 0, __float_as_uint(cx),
                                   __ATOMIC_RELAXED, __HIP_MEMORY_SCOPE_AGENT);
                __hip_atomic_store(co + g * 3 + 1, __float_as_uint(cy),
                                   __ATOMIC_RELAXED, __HIP_MEMORY_SCOPE_AGENT);
                __hip_atomic_store(co + g * 3 + 2, __float_as_uint(cz),
                                   __ATOMIC_RELAXED, __HIP_MEMORY_SCOPE_AGENT);
            }
            const f32x2 cx2 = (f32x2){cx, cx};
            const f32x2 cy2 = (f32x2){cy, cy};
            const f32x2 cz2 = (f32x2){cz, cz};

            // Exact min-dist update: ((dx*dx + dy*dy) + dz*dz), no fma.
#pragma unroll
            for (int j = 0; j < 8; ++j) {
                f32x2 dx = X[j] - cx2;
                f32x2 dy = Y[j] - cy2;
                f32x2 dz = Z[j] - cz2;
                f32x2 d  = (dx * dx + dy * dy) + dz * dz;
                MD[j] = __builtin_elementwise_min(MD[j], d);
            }
            // Per-lane max value.
            f32x2 a0 = __builtin_elementwise_max(MD[0], MD[1]);
            f32x2 a1 = __builtin_elementwise_max(MD[2], MD[3]);
            f32x2 a2 = __builtin_elementwise_max(MD[4], MD[5]);
            f32x2 a3 = __builtin_elementwise_max(MD[6], MD[7]);
            f32x2 b0 = __builtin_elementwise_max(a0, a1);
            f32x2 b1 = __builtin_elementwise_max(a2, a3);
            f32x2 c0 = __builtin_elementwise_max(b0, b1);
            float lmax = fmaxf(c0.x, c0.y);

            // Smallest owned index attaining lmax.
            unsigned candX = 0xFFFFFFFFu, candY = 0xFFFFFFFFu;
#pragma unroll
            for (int j = 7; j >= 0; --j) {
                if (MD[j].y == lmax) candY = (unsigned)(tid + 1024 * j + 512);
                if (MD[j].x == lmax) candX = (unsigned)(tid + 1024 * j);
            }
            unsigned cand = candX < candY ? candX : candY;

            unsigned long long key =
                ((unsigned long long)__float_as_uint(lmax) << 32) | (unsigned)(~cand);
            key = wave_max_u64(key);          // lane 63 valid

            const int par = g & 1;
            if (lane == 63) sk[par][wid] = key;
            __syncthreads();

            unsigned long long m0 = sk[par][0] > sk[par][1] ? sk[par][0] : sk[par][1];
            unsigned long long m1 = sk[par][2] > sk[par][3] ? sk[par][2] : sk[par][3];
            unsigned long long m2 = sk[par][4] > sk[par][5] ? sk[par][4] : sk[par][5];
            unsigned long long m3 = sk[par][6] > sk[par][7] ? sk[par][6] : sk[par][7];
            unsigned long long ma = m0 > m1 ? m0 : m1;
            unsigned long long mb = m2 > m3 ? m2 : m3;
            unsigned long long gk = ma > mb ? ma : mb;
            far = (int)(~(unsigned)gk);

            // Release the chunk [g-7 .. g] to consumers.
            if (tid == 0 && (g & 7) == 7)
                __hip_atomic_store(&progress[b], g + 1,
                                   __ATOMIC_RELEASE, __HIP_MEMORY_SCOPE_AGENT);
        }
        return;
    }

    // ================= consumer: KNN + gather for one (b,g) =================
    const int i = blockIdx.x - BATCH;
    const int b = i & 15;              // g-major: matches production order
    const int g = i >> 4;
    const int bgrow = b * NG + g;

    if (tid == 0) {
        while ((int)__hip_atomic_load(&progress[b], __ATOMIC_ACQUIRE,
                                      __HIP_MEMORY_SCOPE_AGENT) < g + 1)
            __builtin_amdgcn_s_sleep(32);
        unsigned* co = (unsigned*)out1 + (size_t)bgrow * 3;
        sc[0] = __uint_as_float(__hip_atomic_load(co + 0, __ATOMIC_RELAXED,
                                                  __HIP_MEMORY_SCOPE_AGENT));
        sc[1] = __uint_as_float(__hip_atomic_load(co + 1, __ATOMIC_RELAXED,
                                                  __HIP_MEMORY_SCOPE_AGENT));
        sc[2] = __uint_as_float(__hip_atomic_load(co + 2, __ATOMIC_RELAXED,
                                                  __HIP_MEMORY_SCOPE_AGENT));
    }
    __syncthreads();

    const float cx = sc[0], cy = sc[1], cz = sc[2];
    const float q2 = (cx * cx + cy * cy) + cz * cz;   // plain add chain

    const float* xb = xyz + (size_t)b * NPTS * 3;

    // Exact distances for 16 points/thread, packed sortable u64 keys.
    unsigned long long k[16];
#pragma unroll
    for (int j = 0; j < 16; ++j) {
        int p = tid + (j << 9);
        float rx = xb[p * 3 + 0];
        float ry = xb[p * 3 + 1];
        float rz = xb[p * 3 + 2];
        float r2 = (rx * rx + ry * ry) + rz * rz;         // plain add chain
        float dot = fmaf(cz, rz, fmaf(cy, ry, cx * rx));  // fma chain (sgemm-style)
        float d = (q2 + r2) - 2.0f * dot;                 // identical to round 1
        unsigned u = __float_as_uint(d);
        u ^= ((unsigned)((int)u >> 31)) | 0x80000000u;    // sortable float
        k[j] = ((unsigned long long)u << 32) | (unsigned)p;
    }

    unsigned long long lv = min16_u64(k);

    for (int kk = 0; kk < KM; ++kk) {
        unsigned long long w = wave_min_u64(lv);          // lane 63 valid
        const int par = kk & 1;
        if (lane == 63) sk[par][wid] = w;
        __syncthreads();
        unsigned long long m0 = sk[par][0] < sk[par][1] ? sk[par][0] : sk[par][1];
        unsigned long long m1 = sk[par][2] < sk[par][3] ? sk[par][2] : sk[par][3];
        unsigned long long m2 = sk[par][4] < sk[par][5] ? sk[par][4] : sk[par][5];
        unsigned long long m3 = sk[par][6] < sk[par][7] ? sk[par][6] : sk[par][7];
        unsigned long long ma = m0 < m1 ? m0 : m1;
        unsigned long long mb = m2 < m3 ? m2 : m3;
        unsigned long long gk = ma < mb ? ma : mb;
        const unsigned pt = (unsigned)gk;                 // low 32 = point idx
        if ((pt & 511u) == (unsigned)tid) {
            sidx[kk] = (int)pt;
            const unsigned jw = pt >> 9;
#pragma unroll
            for (int j = 0; j < 16; ++j) {
                if ((unsigned)j == jw) k[j] = ~0ULL;
            }
            lv = min16_u64(k);
        }
    }
    __syncthreads();

    // neighborhood: 32 x 3 = 96 floats (exact plain subtract).
    if (tid < 96) {
        int m = tid / 3;
        int c = tid - 3 * m;
        int p = sidx[m];
        float v = xb[p * 3 + c] - sc[c];
        out0[((size_t)bgrow * KM + m) * 3 + c] = v;
    }

    // features: 32 rows x 96 float4 = 3072 float4, 6 per thread.
    const float4* fb = (const float4*)(features + (size_t)b * NPTS * FEATC);
    float4*       ob = (float4*)(out2 + (size_t)bgrow * KM * FEATC);
#pragma unroll
    for (int r = 0; r < 6; ++r) {
        int flat = tid + (r << 9);          // 0..3071
        int m  = flat / 96;
        int c4 = flat - 96 * m;
        float4 v = fb[(size_t)sidx[m] * 96 + c4];
        ob[(size_t)m * 96 + c4] = v;
    }
}

extern "C" void kernel_launch(void* const* d_in, const int* in_sizes, int n_in,
                              void* d_out, int out_size, void* d_ws, size_t ws_size,
                              hipStream_t stream) {
    const float* xyz      = (const float*)d_in[0];
    const float* features = (const float*)d_in[1];
    float* out  = (float*)d_out;
    float* out0 = out + OUT0_OFF;   // neighborhood
    float* out1 = out + OUT1_OFF;   // center
    float* out2 = out + OUT2_OFF;   // feature_group

    int* progress = (int*)d_ws;     // 16 ints

    init_progress<<<1, 64, 0, stream>>>(progress);
    group_kernel<<<BATCH + BATCH * NG, 512, 0, stream>>>(xyz, features,
                                                         out0, out1, out2,
                                                         progress);
}